// Round 2
// baseline (240.993 us; speedup 1.0000x reference)
//
#include <hip/hip_runtime.h>

// SSIM, fused: reflect-pad(1) + five 3x3 box filters + elementwise formula.
// NCHW 32x3x384x640 fp32.
//
// R2: vectorized. Each thread owns a 4-column strip and walks KROWS rows,
// keeping a rolling 3-row window of horizontal 3-tap sums (x, y, x^2, y^2, xy)
// per column in registers. Per row: 2 float4 loads + 4 scalar halo taps
// (L1 hits) serve 4 output pixels; output stored as one float4.

constexpr int HH = 384;
constexpr int WW = 640;
constexpr int KROWS = 8;           // rows per thread
constexpr int TX = 160;            // threads along w: 160 * 4 cols = 640
constexpr int TY = 2;              // row-strips per block -> 320 thr = 5 waves
constexpr float C1 = 0.01f * 0.01f;
constexpr float C2 = 0.03f * 0.03f;

__global__ __launch_bounds__(TX * TY) void ssim_kernel(
    const float* __restrict__ x,
    const float* __restrict__ y,
    float* __restrict__ out)
{
    const int w4 = threadIdx.x * 4;                                // first owned column
    const int h0 = (blockIdx.y * TY + threadIdx.y) * KROWS;        // first owned row
    const size_t pbase = (size_t)blockIdx.z * (size_t)(HH * WW);
    const float* __restrict__ xp = x + pbase;
    const float* __restrict__ yp = y + pbase;
    float* __restrict__ op = out + pbase;

    // reflect (jnp 'reflect': edge NOT repeated): -1 -> 1, W -> W-2
    const int wm = (w4 == 0)       ? 1      : (w4 - 1);
    const int wq = (w4 + 4 == WW)  ? WW - 2 : (w4 + 4);

    float hx[3][4], hy[3][4], hxx[3][4], hyy[3][4], hxy[3][4];

#define LOAD_ROW(R, J) do {                                              \
        int rr = (R);                                                    \
        rr = (rr < 0) ? 1 : ((rr >= HH) ? (HH - 2) : rr);                \
        const float* __restrict__ xr = xp + (size_t)rr * WW;             \
        const float* __restrict__ yr = yp + (size_t)rr * WW;             \
        const float4 xv = *(const float4*)(xr + w4);                     \
        const float4 yv = *(const float4*)(yr + w4);                     \
        const float ax[6] = {xr[wm], xv.x, xv.y, xv.z, xv.w, xr[wq]};    \
        const float ay[6] = {yr[wm], yv.x, yv.y, yv.z, yv.w, yr[wq]};    \
        _Pragma("unroll")                                                \
        for (int c = 0; c < 4; ++c) {                                    \
            hx[J][c]  = ax[c] + ax[c+1] + ax[c+2];                       \
            hy[J][c]  = ay[c] + ay[c+1] + ay[c+2];                       \
            hxx[J][c] = ax[c]*ax[c] + ax[c+1]*ax[c+1] + ax[c+2]*ax[c+2]; \
            hyy[J][c] = ay[c]*ay[c] + ay[c+1]*ay[c+1] + ay[c+2]*ay[c+2]; \
            hxy[J][c] = ax[c]*ay[c] + ax[c+1]*ay[c+1] + ax[c+2]*ay[c+2]; \
        }                                                                \
    } while (0)

    LOAD_ROW(h0 - 1, 0);
    LOAD_ROW(h0,     1);

    const float inv9 = 1.0f / 9.0f;

#pragma unroll
    for (int i = 0; i < KROWS; ++i) {
        const int h = h0 + i;
        LOAD_ROW(h + 1, (i + 2) % 3);

        float4 o;
        float* ov = &o.x;
#pragma unroll
        for (int c = 0; c < 4; ++c) {
            const float sx  = hx[0][c]  + hx[1][c]  + hx[2][c];
            const float sy  = hy[0][c]  + hy[1][c]  + hy[2][c];
            const float sxx = hxx[0][c] + hxx[1][c] + hxx[2][c];
            const float syy = hyy[0][c] + hyy[1][c] + hyy[2][c];
            const float sxy = hxy[0][c] + hxy[1][c] + hxy[2][c];

            const float mux  = sx * inv9;
            const float muy  = sy * inv9;
            const float varx = sxx * inv9 - mux * mux;
            const float vary = syy * inv9 - muy * muy;
            const float cov  = sxy * inv9 - mux * muy;

            const float num = (2.0f * mux * muy + C1) * (2.0f * cov + C2);
            const float den = (mux * mux + muy * muy + C1) * (varx + vary + C2);
#if __has_builtin(__builtin_amdgcn_rcpf)
            float s = num * __builtin_amdgcn_rcpf(den);
#else
            float s = num / den;
#endif
            s = fminf(fmaxf(s, 0.0f), 1.0f);
            ov[c] = s;
        }
        *(float4*)(op + (size_t)h * WW + w4) = o;
    }
#undef LOAD_ROW
}

extern "C" void kernel_launch(void* const* d_in, const int* in_sizes, int n_in,
                              void* d_out, int out_size, void* d_ws, size_t ws_size,
                              hipStream_t stream) {
    const float* x = (const float*)d_in[0];
    const float* y = (const float*)d_in[1];
    float* out = (float*)d_out;

    const int planes = in_sizes[0] / (HH * WW);        // 32*3 = 96
    dim3 grid(1, HH / (TY * KROWS), planes);           // (1, 24, 96)
    dim3 block(TX, TY);                                // 320 threads = 5 waves
    ssim_kernel<<<grid, block, 0, stream>>>(x, y, out);
}